// Round 3
// baseline (2770.737 us; speedup 1.0000x reference)
//
#include <hip/hip_runtime.h>
#include <hip/hip_bf16.h>
#include <math.h>

#define CD 128
#define HH 4
#define DH 32
#define LL 2

using bf16 = __hip_bfloat16;

__device__ __forceinline__ float bfbits2f(unsigned int s) {
  return __uint_as_float(s << 16);
}

__device__ __forceinline__ float gelu_f(float x) {
  return 0.5f * x * (1.0f + erff(x * 0.70710678118654752f));
}

// order-preserving float <-> uint mapping for atomicMax
__device__ __forceinline__ unsigned int f2ord(float f) {
  unsigned int u = __float_as_uint(f);
  return (u & 0x80000000u) ? ~u : (u | 0x80000000u);
}
__device__ __forceinline__ float ord2f(unsigned int u) {
  unsigned int b = (u & 0x80000000u) ? (u & 0x7FFFFFFFu) : ~u;
  return __uint_as_float(b);
}

// ---- detect input formats: flags[0]=floats-are-f32, flags[1]=edge-index-is-i64 ----
__global__ void k_detect(const void* __restrict__ x, const int* __restrict__ ei,
                         int* __restrict__ flags) {
  __shared__ int cnt_f32, cnt_i32;
  if (threadIdx.x == 0) { cnt_f32 = 0; cnt_i32 = 0; }
  __syncthreads();
  int t = threadIdx.x;  // 128 threads
  unsigned short u = ((const unsigned short*)x)[2 * t];
  float v = bfbits2f((unsigned int)u);
  float av = fabsf(v);
  if (av != 0.f && (av > 1e8f || av < 1e-8f)) atomicAdd(&cnt_f32, 1);
  if (t < 64) {
    if (((const int*)ei)[2 * t + 1] != 0) atomicAdd(&cnt_i32, 1);
  }
  __syncthreads();
  if (threadIdx.x == 0) {
    flags[0] = (cnt_f32 > 8) ? 1 : 0;
    flags[1] = (cnt_i32 == 0) ? 1 : 0;
  }
}

// ---- normalize any float input (bf16 or f32) to f32 ----
__global__ void k_cvt(const void* __restrict__ in, float* __restrict__ out, int n,
                      const int* __restrict__ flags) {
  int i = blockIdx.x * blockDim.x + threadIdx.x;
  if (i >= n) return;
  if (flags[0]) out[i] = ((const float*)in)[i];
  else out[i] = bfbits2f((unsigned int)((const unsigned short*)in)[i]);
}

__device__ __forceinline__ int edge_idx(const int* __restrict__ ei, long pos, int is64) {
  return is64 ? ei[2 * pos] : ei[pos];
}

// ---- Weff[c][h*DH+e] = sum_d W[c][h*DH+d] * rel[h][d][e] (all f32) ----
__global__ void k_eff_w(const float* __restrict__ W, const float* __restrict__ rel,
                        float* __restrict__ Weff) {
  int c = blockIdx.x, h = blockIdx.y, e = threadIdx.x;
  float acc = 0.f;
#pragma unroll
  for (int d = 0; d < DH; d++)
    acc += W[c * CD + h * DH + d] * rel[h * DH * DH + d * DH + e];
  Weff[c * CD + h * DH + e] = acc;
}

__global__ void k_eff_b(const float* __restrict__ b, const float* __restrict__ rel,
                        float* __restrict__ beff) {
  int h = blockIdx.x, e = threadIdx.x;
  float acc = 0.f;
#pragma unroll
  for (int d = 0; d < DH; d++)
    acc += b[h * DH + d] * rel[h * DH * DH + d * DH + e];
  beff[h * DH + e] = acc;
}

// ---- y[N,128] = (GELU?)(x[N,128]) @ W[128,128] + b ; all f32 ----
template <bool GELU>
__global__ __launch_bounds__(256) void k_gemm(const float* __restrict__ xin,
                                              const float* __restrict__ win,
                                              const float* __restrict__ bin,
                                              float* __restrict__ y, int nrows) {
  __shared__ float xs[128][CD];
  const int t = threadIdx.x;
  const int r0 = blockIdx.x * 128;
#pragma unroll
  for (int it = 0; it < 16; it++) {
    int idx = t + it * 256;       // 4096 float4 chunks
    int r = idx >> 5;             // 32 chunks per row
    int c4 = (idx & 31) * 4;
    int gr = r0 + r;
    float4 f = make_float4(0.f, 0.f, 0.f, 0.f);
    if (gr < nrows) f = *(const float4*)(xin + (size_t)gr * CD + c4);
    if (GELU) {
      f.x = gelu_f(f.x); f.y = gelu_f(f.y);
      f.z = gelu_f(f.z); f.w = gelu_f(f.w);
    }
    *(float4*)&xs[r][c4] = f;
  }
  __syncthreads();
  const int tx = t & 31, ty = t >> 5;  // ty in [0,8)
  float acc[16][4];
#pragma unroll
  for (int rr = 0; rr < 16; rr++)
#pragma unroll
    for (int cc = 0; cc < 4; cc++) acc[rr][cc] = bin[tx + 32 * cc];

  for (int k = 0; k < CD; k++) {
    float wv[4];
#pragma unroll
    for (int cc = 0; cc < 4; cc++) wv[cc] = win[k * CD + tx + 32 * cc];
#pragma unroll
    for (int rr = 0; rr < 16; rr++) {
      float xv = xs[ty * 16 + rr][k];
#pragma unroll
      for (int cc = 0; cc < 4; cc++) acc[rr][cc] += xv * wv[cc];
    }
  }
#pragma unroll
  for (int rr = 0; rr < 16; rr++) {
    int gr = r0 + ty * 16 + rr;
    if (gr < nrows) {
#pragma unroll
      for (int cc = 0; cc < 4; cc++)
        y[(size_t)gr * CD + tx + 32 * cc] = acc[rr][cc];
    }
  }
}

// ---- per-edge logits + segment max (32 lanes per edge) ----
__global__ __launch_bounds__(256) void k_alpha(
    const float* __restrict__ q, const float* __restrict__ kk,
    const int* __restrict__ ei, const float* __restrict__ p_rel,
    float* __restrict__ alpha, unsigned int* __restrict__ amax,
    const int* __restrict__ flags, int E, int Nn) {
  int g = (blockIdx.x * 256 + threadIdx.x) >> 5;
  int lane = threadIdx.x & 31;
  if (g >= E) return;
  int is64 = flags[1];
  int s = edge_idx(ei, g, is64);
  int d = edge_idx(ei, (long)E + g, is64);
  if ((unsigned)s >= (unsigned)Nn) s = 0;
  if ((unsigned)d >= (unsigned)Nn) d = 0;
  const float* qr = q + (size_t)d * CD;
  const float* kr = kk + (size_t)s * CD;
  float p0 = qr[lane] * kr[lane];
  float p1 = qr[lane + 32] * kr[lane + 32];
  float p2 = qr[lane + 64] * kr[lane + 64];
  float p3 = qr[lane + 96] * kr[lane + 96];
#pragma unroll
  for (int off = 16; off; off >>= 1) {
    p0 += __shfl_xor(p0, off);
    p1 += __shfl_xor(p1, off);
    p2 += __shfl_xor(p2, off);
    p3 += __shfl_xor(p3, off);
  }
  if (lane < 4) {
    float pv = (lane == 0) ? p0 : (lane == 1) ? p1 : (lane == 2) ? p2 : p3;
    float a = pv * p_rel[lane] * 0.17677669529663687f;  // 1/sqrt(32)
    alpha[(size_t)g * 4 + lane] = a;
    atomicMax(&amax[d * 4 + lane], f2ord(a));
  }
}

// ---- ez = exp(alpha - amax[dst]); denom += ez ----
__global__ void k_soft(float* __restrict__ alpha, const int* __restrict__ ei,
                       const unsigned int* __restrict__ amax,
                       float* __restrict__ denom, const int* __restrict__ flags,
                       int E, int Nn) {
  int i = blockIdx.x * blockDim.x + threadIdx.x;
  if (i >= 4 * E) return;
  int e = i >> 2, h = i & 3;
  int is64 = flags[1];
  int d = edge_idx(ei, (long)E + e, is64);
  if ((unsigned)d >= (unsigned)Nn) d = 0;
  float am = ord2f(amax[d * 4 + h]);
  float ez = __expf(alpha[i] - am);
  alpha[i] = ez;
  unsafeAtomicAdd(&denom[d * 4 + h], ez);
}

// ---- agg[dst] += v[src] * attn (32 lanes per edge) ----
__global__ __launch_bounds__(256) void k_msg(
    const float* __restrict__ v, const float* __restrict__ alpha,
    const float* __restrict__ denom, const int* __restrict__ ei,
    float* __restrict__ agg, const int* __restrict__ flags, int E, int Nn) {
  int g = (blockIdx.x * 256 + threadIdx.x) >> 5;
  int lane = threadIdx.x & 31;
  if (g >= E) return;
  int is64 = flags[1];
  int s = edge_idx(ei, g, is64);
  int d = edge_idx(ei, (long)E + g, is64);
  if ((unsigned)s >= (unsigned)Nn) s = 0;
  if ((unsigned)d >= (unsigned)Nn) d = 0;
  float4 ez = *(const float4*)(alpha + (size_t)g * 4);
  float4 dn = *(const float4*)(denom + (size_t)d * 4);
  float at[4];
  at[0] = dn.x > 0.f ? ez.x / dn.x : 0.f;
  at[1] = dn.y > 0.f ? ez.y / dn.y : 0.f;
  at[2] = dn.z > 0.f ? ez.z / dn.z : 0.f;
  at[3] = dn.w > 0.f ? ez.w / dn.w : 0.f;
  const float* vr = v + (size_t)s * CD;
  float* ar = agg + (size_t)d * CD;
#pragma unroll
  for (int j = 0; j < 4; j++)
    unsafeAtomicAdd(&ar[lane + 32 * j], vr[lane + 32 * j] * at[j]);
}

// ---- h = g*out + (1-g)*h ----
__global__ void k_gate(float* __restrict__ h, const float* __restrict__ ob,
                       const float* __restrict__ skip, int n4) {
  int i = blockIdx.x * blockDim.x + threadIdx.x;
  if (i >= n4) return;
  float s = skip[0];
  float g = 1.f / (1.f + __expf(-s));
  float4 hv = ((const float4*)h)[i];
  float4 ov = ((const float4*)ob)[i];
  hv.x = g * ov.x + (1.f - g) * hv.x;
  hv.y = g * ov.y + (1.f - g) * hv.y;
  hv.z = g * ov.z + (1.f - g) * hv.z;
  hv.w = g * ov.w + (1.f - g) * hv.w;
  ((float4*)h)[i] = hv;
}

// ---- out[n,0:2] = h[n,:] @ Wfc + bfc; f32 out if flags[0] else bf16 ----
__global__ __launch_bounds__(256) void k_final(const float* __restrict__ h,
                                               const float* __restrict__ Wfc,
                                               const float* __restrict__ bfc,
                                               void* __restrict__ out,
                                               const int* __restrict__ flags, int N) {
  int g = (blockIdx.x * 256 + threadIdx.x) >> 5;
  int lane = threadIdx.x & 31;
  if (g >= N) return;
  const float* hr = h + (size_t)g * CD;
  float a0 = 0.f, a1 = 0.f;
#pragma unroll
  for (int j = 0; j < 4; j++) {
    float hv = hr[lane + 32 * j];
    a0 += hv * Wfc[(lane + 32 * j) * 2];
    a1 += hv * Wfc[(lane + 32 * j) * 2 + 1];
  }
#pragma unroll
  for (int off = 16; off; off >>= 1) {
    a0 += __shfl_xor(a0, off);
    a1 += __shfl_xor(a1, off);
  }
  if (lane == 0) {
    float o0 = a0 + bfc[0];
    float o1 = a1 + bfc[1];
    if (flags[0]) {  // f32 inputs -> f32 output (reference dtype)
      ((float*)out)[(size_t)g * 2] = o0;
      ((float*)out)[(size_t)g * 2 + 1] = o1;
    } else {         // bf16 inputs -> bf16 output
      ((bf16*)out)[(size_t)g * 2] = __float2bfloat16(o0);
      ((bf16*)out)[(size_t)g * 2 + 1] = __float2bfloat16(o1);
    }
  }
}

extern "C" void kernel_launch(void* const* d_in, const int* in_sizes, int n_in,
                              void* d_out, int out_size, void* d_ws, size_t ws_size,
                              hipStream_t stream) {
  const int* ei = (const int*)d_in[1];
  const int N = in_sizes[0] / CD;
  const int E = in_sizes[1] / 2;
  const size_t NC = (size_t)N * CD;

  float* p = (float*)d_ws;
  float* hbuf = p;                 // NC  activations (f32)
  float* qbuf = p + NC;            // NC  q; reused as agg
  float* kbuf = p + 2 * NC;        // NC  k; reused as GEMM-out
  float* vbuf = p + 3 * NC;        // NC
  float* alpha = p + 4 * NC;       // 4E  logits -> ez in place
  unsigned int* amax = (unsigned int*)(alpha + (size_t)4 * E);  // 4N
  float* denom = (float*)amax + (size_t)4 * N;                  // 4N
  float* cur = denom + (size_t)4 * N;
  float* wkeff = cur; cur += CD * CD;
  float* bkeff = cur; cur += CD;
  float* wveff = cur; cur += CD * CD;
  float* bveff = cur; cur += CD;
  // normalized-to-f32 parameter block
  float* pWk = cur; cur += (size_t)LL * CD * CD;
  float* pbk = cur; cur += (size_t)LL * CD;
  float* pWq = cur; cur += (size_t)LL * CD * CD;
  float* pbq = cur; cur += (size_t)LL * CD;
  float* pWv = cur; cur += (size_t)LL * CD * CD;
  float* pbv = cur; cur += (size_t)LL * CD;
  float* par = cur; cur += (size_t)LL * HH * DH * DH;
  float* pmr = cur; cur += (size_t)LL * HH * DH * DH;
  float* ppr = cur; cur += (size_t)LL * HH;
  float* pWa = cur; cur += (size_t)LL * CD * CD;
  float* pba = cur; cur += (size_t)LL * CD;
  float* pskip = cur; cur += LL;
  float* pWfc = cur; cur += (size_t)CD * 2;
  float* pbfc = cur; cur += 2;
  int* flags = (int*)cur;

  k_detect<<<1, 128, 0, stream>>>(d_in[0], ei, flags);

  // normalize all float inputs to f32
  struct CvtJob { const void* in; float* out; int n; };
  const CvtJob jobs[] = {
      {d_in[0], hbuf, (int)NC},
      {d_in[2], pWk, LL * CD * CD}, {d_in[3], pbk, LL * CD},
      {d_in[4], pWq, LL * CD * CD}, {d_in[5], pbq, LL * CD},
      {d_in[6], pWv, LL * CD * CD}, {d_in[7], pbv, LL * CD},
      {d_in[8], par, LL * HH * DH * DH}, {d_in[9], pmr, LL * HH * DH * DH},
      {d_in[10], ppr, LL * HH},
      {d_in[11], pWa, LL * CD * CD}, {d_in[12], pba, LL * CD},
      {d_in[13], pskip, LL},
      {d_in[14], pWfc, CD * 2}, {d_in[15], pbfc, 2},
  };
  for (const auto& j : jobs)
    k_cvt<<<(j.n + 255) / 256, 256, 0, stream>>>(j.in, j.out, j.n, flags);

  const int gemmBlocks = (N + 127) / 128;
  for (int l = 0; l < LL; l++) {
    const float* Wk_l = pWk + (size_t)l * CD * CD;
    const float* bk_l = pbk + (size_t)l * CD;
    const float* Wq_l = pWq + (size_t)l * CD * CD;
    const float* bq_l = pbq + (size_t)l * CD;
    const float* Wv_l = pWv + (size_t)l * CD * CD;
    const float* bv_l = pbv + (size_t)l * CD;
    const float* ar_l = par + (size_t)l * HH * DH * DH;
    const float* mr_l = pmr + (size_t)l * HH * DH * DH;
    const float* pr_l = ppr + (size_t)l * HH;
    const float* Wa_l = pWa + (size_t)l * CD * CD;
    const float* ba_l = pba + (size_t)l * CD;

    // fold relation transforms into K/V weights
    k_eff_w<<<dim3(CD, HH), DH, 0, stream>>>(Wk_l, ar_l, wkeff);
    k_eff_w<<<dim3(CD, HH), DH, 0, stream>>>(Wv_l, mr_l, wveff);
    k_eff_b<<<HH, DH, 0, stream>>>(bk_l, ar_l, bkeff);
    k_eff_b<<<HH, DH, 0, stream>>>(bv_l, mr_l, bveff);

    // q/k/v projections
    k_gemm<false><<<gemmBlocks, 256, 0, stream>>>(hbuf, Wq_l, bq_l, qbuf, N);
    k_gemm<false><<<gemmBlocks, 256, 0, stream>>>(hbuf, wkeff, bkeff, kbuf, N);
    k_gemm<false><<<gemmBlocks, 256, 0, stream>>>(hbuf, wveff, bveff, vbuf, N);

    hipMemsetAsync(amax, 0, (size_t)4 * N * sizeof(unsigned int), stream);
    hipMemsetAsync(denom, 0, (size_t)4 * N * sizeof(float), stream);

    k_alpha<<<(E + 7) / 8, 256, 0, stream>>>(qbuf, kbuf, ei, pr_l, alpha, amax, flags, E, N);
    k_soft<<<(4 * E + 255) / 256, 256, 0, stream>>>(alpha, ei, amax, denom, flags, E, N);

    hipMemsetAsync(qbuf, 0, NC * sizeof(float), stream);  // agg := 0
    k_msg<<<(E + 7) / 8, 256, 0, stream>>>(vbuf, alpha, denom, ei, qbuf, flags, E, N);

    // out = gelu(agg) @ Wa + ba -> kbuf; then gated residual into hbuf
    k_gemm<true><<<gemmBlocks, 256, 0, stream>>>(qbuf, Wa_l, ba_l, kbuf, N);
    k_gate<<<((int)(NC / 4) + 255) / 256, 256, 0, stream>>>(hbuf, kbuf, pskip + l, (int)(NC / 4));
  }
  k_final<<<(N + 7) / 8, 256, 0, stream>>>(hbuf, pWfc, pbfc, d_out, flags, N);
}

// Round 4
// 1487.919 us; speedup vs baseline: 1.8622x; 1.8622x over previous
//
#include <hip/hip_runtime.h>
#include <hip/hip_bf16.h>
#include <math.h>

#define CD 128
#define HH 4
#define DH 32
#define LL 2

using bf16 = __hip_bfloat16;

__device__ __forceinline__ float bfbits2f(unsigned int s) {
  return __uint_as_float(s << 16);
}

__device__ __forceinline__ float gelu_f(float x) {
  return 0.5f * x * (1.0f + erff(x * 0.70710678118654752f));
}

// ---- detect input formats: flags[0]=floats-are-f32, flags[1]=edge-index-is-i64 ----
__global__ void k_detect(const void* __restrict__ x, const int* __restrict__ ei,
                         int* __restrict__ flags) {
  __shared__ int cnt_f32, cnt_i32;
  if (threadIdx.x == 0) { cnt_f32 = 0; cnt_i32 = 0; }
  __syncthreads();
  int t = threadIdx.x;  // 128 threads
  unsigned short u = ((const unsigned short*)x)[2 * t];
  float v = bfbits2f((unsigned int)u);
  float av = fabsf(v);
  if (av != 0.f && (av > 1e8f || av < 1e-8f)) atomicAdd(&cnt_f32, 1);
  if (t < 64) {
    if (((const int*)ei)[2 * t + 1] != 0) atomicAdd(&cnt_i32, 1);
  }
  __syncthreads();
  if (threadIdx.x == 0) {
    flags[0] = (cnt_f32 > 8) ? 1 : 0;
    flags[1] = (cnt_i32 == 0) ? 1 : 0;
  }
}

// ---- normalize any float input (bf16 or f32) to f32 ----
__global__ void k_cvt(const void* __restrict__ in, float* __restrict__ out, int n,
                      const int* __restrict__ flags) {
  int i = blockIdx.x * blockDim.x + threadIdx.x;
  if (i >= n) return;
  if (flags[0]) out[i] = ((const float*)in)[i];
  else out[i] = bfbits2f((unsigned int)((const unsigned short*)in)[i]);
}

__device__ __forceinline__ int edge_idx(const int* __restrict__ ei, long pos, int is64) {
  return is64 ? ei[2 * pos] : ei[pos];
}

// ---- Weff[c][h*DH+e] = sum_d W[c][h*DH+d] * rel[h][d][e] (all f32) ----
__global__ void k_eff_w(const float* __restrict__ W, const float* __restrict__ rel,
                        float* __restrict__ Weff) {
  int c = blockIdx.x, h = blockIdx.y, e = threadIdx.x;
  float acc = 0.f;
#pragma unroll
  for (int d = 0; d < DH; d++)
    acc += W[c * CD + h * DH + d] * rel[h * DH * DH + d * DH + e];
  Weff[c * CD + h * DH + e] = acc;
}

__global__ void k_eff_b(const float* __restrict__ b, const float* __restrict__ rel,
                        float* __restrict__ beff) {
  int h = blockIdx.x, e = threadIdx.x;
  float acc = 0.f;
#pragma unroll
  for (int d = 0; d < DH; d++)
    acc += b[h * DH + d] * rel[h * DH * DH + d * DH + e];
  beff[h * DH + e] = acc;
}

// ---- y[N,128] = (GELU?)(x[N,128]) @ W[128,128] + b ; all f32 ----
template <bool GELU>
__global__ __launch_bounds__(256) void k_gemm(const float* __restrict__ xin,
                                              const float* __restrict__ win,
                                              const float* __restrict__ bin,
                                              float* __restrict__ y, int nrows) {
  __shared__ float xs[128][CD];
  const int t = threadIdx.x;
  const int r0 = blockIdx.x * 128;
#pragma unroll
  for (int it = 0; it < 16; it++) {
    int idx = t + it * 256;       // 4096 float4 chunks
    int r = idx >> 5;             // 32 chunks per row
    int c4 = (idx & 31) * 4;
    int gr = r0 + r;
    float4 f = make_float4(0.f, 0.f, 0.f, 0.f);
    if (gr < nrows) f = *(const float4*)(xin + (size_t)gr * CD + c4);
    if (GELU) {
      f.x = gelu_f(f.x); f.y = gelu_f(f.y);
      f.z = gelu_f(f.z); f.w = gelu_f(f.w);
    }
    *(float4*)&xs[r][c4] = f;
  }
  __syncthreads();
  const int tx = t & 31, ty = t >> 5;  // ty in [0,8)
  float acc[16][4];
#pragma unroll
  for (int rr = 0; rr < 16; rr++)
#pragma unroll
    for (int cc = 0; cc < 4; cc++) acc[rr][cc] = bin[tx + 32 * cc];

  for (int k = 0; k < CD; k++) {
    float wv[4];
#pragma unroll
    for (int cc = 0; cc < 4; cc++) wv[cc] = win[k * CD + tx + 32 * cc];
#pragma unroll
    for (int rr = 0; rr < 16; rr++) {
      float xv = xs[ty * 16 + rr][k];
#pragma unroll
      for (int cc = 0; cc < 4; cc++) acc[rr][cc] += xv * wv[cc];
    }
  }
#pragma unroll
  for (int rr = 0; rr < 16; rr++) {
    int gr = r0 + ty * 16 + rr;
    if (gr < nrows) {
#pragma unroll
      for (int cc = 0; cc < 4; cc++)
        y[(size_t)gr * CD + tx + 32 * cc] = acc[rr][cc];
    }
  }
}

// ==== CSR build ====
__global__ void k_hist(const int* __restrict__ ei, int* __restrict__ deg,
                       const int* __restrict__ flags, int E, int Nn) {
  int i = blockIdx.x * blockDim.x + threadIdx.x;
  if (i >= E) return;
  int d = edge_idx(ei, (long)E + i, flags[1]);
  if ((unsigned)d >= (unsigned)Nn) d = 0;
  atomicAdd(&deg[d], 1);
}

__global__ void k_scan1(const int* __restrict__ deg, int* __restrict__ tmp,
                        int* __restrict__ bsum, int n) {
  __shared__ int sh[256];
  int i = blockIdx.x * 256 + threadIdx.x;
  int v = (i < n) ? deg[i] : 0;
  sh[threadIdx.x] = v;
  __syncthreads();
  for (int off = 1; off < 256; off <<= 1) {
    int t = (threadIdx.x >= off) ? sh[threadIdx.x - off] : 0;
    __syncthreads();
    sh[threadIdx.x] += t;
    __syncthreads();
  }
  if (i < n) tmp[i] = sh[threadIdx.x];
  if (threadIdx.x == 255) bsum[blockIdx.x] = sh[255];
}

__global__ void k_scan2(int* __restrict__ bsum, int nb) {
  __shared__ int sh[256];
  __shared__ int carry;
  if (threadIdx.x == 0) carry = 0;
  __syncthreads();
  for (int base = 0; base < nb; base += 256) {
    int i = base + threadIdx.x;
    int v = (i < nb) ? bsum[i] : 0;
    sh[threadIdx.x] = v;
    __syncthreads();
    for (int off = 1; off < 256; off <<= 1) {
      int t = (threadIdx.x >= off) ? sh[threadIdx.x - off] : 0;
      __syncthreads();
      sh[threadIdx.x] += t;
      __syncthreads();
    }
    if (i < nb) bsum[i] = sh[threadIdx.x] + carry;
    __syncthreads();
    if (threadIdx.x == 0) carry += sh[255];
    __syncthreads();
  }
}

__global__ void k_scan3(const int* __restrict__ tmp, const int* __restrict__ deg,
                        const int* __restrict__ bsum, int* __restrict__ rowptr,
                        int* __restrict__ fill, int n) {
  int i = blockIdx.x * 256 + threadIdx.x;
  if (i >= n) return;
  int off = (blockIdx.x > 0) ? bsum[blockIdx.x - 1] : 0;
  int excl = tmp[i] - deg[i] + off;
  rowptr[i] = excl;
  fill[i] = excl;
}

__global__ void k_scatter(const int* __restrict__ ei, int* __restrict__ fill,
                          int* __restrict__ csr_src, const int* __restrict__ flags,
                          int E, int Nn) {
  int i = blockIdx.x * blockDim.x + threadIdx.x;
  if (i >= E) return;
  int is64 = flags[1];
  int s = edge_idx(ei, i, is64);
  int d = edge_idx(ei, (long)E + i, is64);
  if ((unsigned)s >= (unsigned)Nn) s = 0;
  if ((unsigned)d >= (unsigned)Nn) d = 0;
  int pos = atomicAdd(&fill[d], 1);
  csr_src[pos] = s;
}

// ==== fused per-dst-node attention: logits + online softmax + weighted agg ====
// one wave (64 lanes) per node; lane l covers dims {l, l+64} -> heads {l>>5, 2+(l>>5)}
__global__ __launch_bounds__(256) void k_edge(
    const float* __restrict__ q, const float* __restrict__ kk,
    const float* __restrict__ v, const int* __restrict__ rowptr,
    const int* __restrict__ deg, const int* __restrict__ csr_src,
    const float* __restrict__ p_rel, float* __restrict__ agg, int N) {
  int n = (blockIdx.x * 256 + threadIdx.x) >> 6;
  int l = threadIdx.x & 63;
  if (n >= N) return;
  const int start = rowptr[n];
  const int cnt = deg[n];
  const int h_lo = l >> 5;
  const float prl_lo = p_rel[h_lo] * 0.17677669529663687f;      // 1/sqrt(32)
  const float prl_hi = p_rel[2 + h_lo] * 0.17677669529663687f;
  const float q_lo = q[(size_t)n * CD + l];
  const float q_hi = q[(size_t)n * CD + 64 + l];
  float m_lo = -INFINITY, m_hi = -INFINITY;
  float den_lo = 0.f, den_hi = 0.f, acc_lo = 0.f, acc_hi = 0.f;
  for (int e = start; e < start + cnt; e++) {
    int s = csr_src[e];
    const float* kr = kk + (size_t)s * CD;
    const float* vr = v + (size_t)s * CD;
    float k0 = kr[l], k1 = kr[64 + l];
    float v0 = vr[l], v1 = vr[64 + l];
    float p_lo = q_lo * k0;
    float p_hi = q_hi * k1;
#pragma unroll
    for (int off = 16; off; off >>= 1) {  // masks <32 stay within 32-lane head groups
      p_lo += __shfl_xor(p_lo, off);
      p_hi += __shfl_xor(p_hi, off);
    }
    float a_lo = p_lo * prl_lo;
    float a_hi = p_hi * prl_hi;
    float mn_lo = fmaxf(m_lo, a_lo);
    float mn_hi = fmaxf(m_hi, a_hi);
    float sc_lo = __expf(m_lo - mn_lo);  // first iter: exp(-inf)=0
    float sc_hi = __expf(m_hi - mn_hi);
    float e_lo = __expf(a_lo - mn_lo);
    float e_hi = __expf(a_hi - mn_hi);
    acc_lo = acc_lo * sc_lo + e_lo * v0;
    acc_hi = acc_hi * sc_hi + e_hi * v1;
    den_lo = den_lo * sc_lo + e_lo;
    den_hi = den_hi * sc_hi + e_hi;
    m_lo = mn_lo;
    m_hi = mn_hi;
  }
  agg[(size_t)n * CD + l] = (den_lo > 0.f) ? acc_lo / den_lo : 0.f;
  agg[(size_t)n * CD + 64 + l] = (den_hi > 0.f) ? acc_hi / den_hi : 0.f;
}

// ---- h = g*out + (1-g)*h ----
__global__ void k_gate(float* __restrict__ h, const float* __restrict__ ob,
                       const float* __restrict__ skip, int n4) {
  int i = blockIdx.x * blockDim.x + threadIdx.x;
  if (i >= n4) return;
  float s = skip[0];
  float g = 1.f / (1.f + __expf(-s));
  float4 hv = ((const float4*)h)[i];
  float4 ov = ((const float4*)ob)[i];
  hv.x = g * ov.x + (1.f - g) * hv.x;
  hv.y = g * ov.y + (1.f - g) * hv.y;
  hv.z = g * ov.z + (1.f - g) * hv.z;
  hv.w = g * ov.w + (1.f - g) * hv.w;
  ((float4*)h)[i] = hv;
}

// ---- out[n,0:2] = h[n,:] @ Wfc + bfc; f32 out if flags[0] else bf16 ----
__global__ __launch_bounds__(256) void k_final(const float* __restrict__ h,
                                               const float* __restrict__ Wfc,
                                               const float* __restrict__ bfc,
                                               void* __restrict__ out,
                                               const int* __restrict__ flags, int N) {
  int g = (blockIdx.x * 256 + threadIdx.x) >> 5;
  int lane = threadIdx.x & 31;
  if (g >= N) return;
  const float* hr = h + (size_t)g * CD;
  float a0 = 0.f, a1 = 0.f;
#pragma unroll
  for (int j = 0; j < 4; j++) {
    float hv = hr[lane + 32 * j];
    a0 += hv * Wfc[(lane + 32 * j) * 2];
    a1 += hv * Wfc[(lane + 32 * j) * 2 + 1];
  }
#pragma unroll
  for (int off = 16; off; off >>= 1) {
    a0 += __shfl_xor(a0, off);
    a1 += __shfl_xor(a1, off);
  }
  if (lane == 0) {
    float o0 = a0 + bfc[0];
    float o1 = a1 + bfc[1];
    if (flags[0]) {
      ((float*)out)[(size_t)g * 2] = o0;
      ((float*)out)[(size_t)g * 2 + 1] = o1;
    } else {
      ((bf16*)out)[(size_t)g * 2] = __float2bfloat16(o0);
      ((bf16*)out)[(size_t)g * 2 + 1] = __float2bfloat16(o1);
    }
  }
}

extern "C" void kernel_launch(void* const* d_in, const int* in_sizes, int n_in,
                              void* d_out, int out_size, void* d_ws, size_t ws_size,
                              hipStream_t stream) {
  const int* ei = (const int*)d_in[1];
  const int N = in_sizes[0] / CD;
  const int E = in_sizes[1] / 2;
  const size_t NC = (size_t)N * CD;
  const int nB = (N + 255) / 256;  // scan blocks

  float* p = (float*)d_ws;
  float* hbuf = p;                 // NC  activations (f32)
  float* qbuf = p + NC;            // NC  q; reused as agg
  float* kbuf = p + 2 * NC;        // NC  k; reused as GEMM-out
  float* vbuf = p + 3 * NC;        // NC
  // CSR region
  int* ip = (int*)(p + 4 * NC);
  int* deg = ip;                   // N
  int* tmp = ip + N;               // N
  int* rowptr = ip + 2 * N;        // N
  int* fill = ip + 3 * N;          // N
  int* bsum = ip + 4 * N;          // nB
  int* csr_src = ip + 4 * N + nB;  // E
  float* cur = (float*)(csr_src + E);
  float* wkeff = cur; cur += CD * CD;
  float* bkeff = cur; cur += CD;
  float* wveff = cur; cur += CD * CD;
  float* bveff = cur; cur += CD;
  // normalized-to-f32 parameter block
  float* pWk = cur; cur += (size_t)LL * CD * CD;
  float* pbk = cur; cur += (size_t)LL * CD;
  float* pWq = cur; cur += (size_t)LL * CD * CD;
  float* pbq = cur; cur += (size_t)LL * CD;
  float* pWv = cur; cur += (size_t)LL * CD * CD;
  float* pbv = cur; cur += (size_t)LL * CD;
  float* par = cur; cur += (size_t)LL * HH * DH * DH;
  float* pmr = cur; cur += (size_t)LL * HH * DH * DH;
  float* ppr = cur; cur += (size_t)LL * HH;
  float* pWa = cur; cur += (size_t)LL * CD * CD;
  float* pba = cur; cur += (size_t)LL * CD;
  float* pskip = cur; cur += LL;
  float* pWfc = cur; cur += (size_t)CD * 2;
  float* pbfc = cur; cur += 2;
  int* flags = (int*)cur;

  k_detect<<<1, 128, 0, stream>>>(d_in[0], ei, flags);

  // normalize all float inputs to f32
  struct CvtJob { const void* in; float* out; int n; };
  const CvtJob jobs[] = {
      {d_in[0], hbuf, (int)NC},
      {d_in[2], pWk, LL * CD * CD}, {d_in[3], pbk, LL * CD},
      {d_in[4], pWq, LL * CD * CD}, {d_in[5], pbq, LL * CD},
      {d_in[6], pWv, LL * CD * CD}, {d_in[7], pbv, LL * CD},
      {d_in[8], par, LL * HH * DH * DH}, {d_in[9], pmr, LL * HH * DH * DH},
      {d_in[10], ppr, LL * HH},
      {d_in[11], pWa, LL * CD * CD}, {d_in[12], pba, LL * CD},
      {d_in[13], pskip, LL},
      {d_in[14], pWfc, CD * 2}, {d_in[15], pbfc, 2},
  };
  for (const auto& j : jobs)
    k_cvt<<<(j.n + 255) / 256, 256, 0, stream>>>(j.in, j.out, j.n, flags);

  // ---- build CSR by dst (once; edge list is layer-invariant) ----
  hipMemsetAsync(deg, 0, (size_t)N * sizeof(int), stream);
  k_hist<<<(E + 255) / 256, 256, 0, stream>>>(ei, deg, flags, E, N);
  k_scan1<<<nB, 256, 0, stream>>>(deg, tmp, bsum, N);
  k_scan2<<<1, 256, 0, stream>>>(bsum, nB);
  k_scan3<<<nB, 256, 0, stream>>>(tmp, deg, bsum, rowptr, fill, N);
  k_scatter<<<(E + 255) / 256, 256, 0, stream>>>(ei, fill, csr_src, flags, E, N);

  const int gemmBlocks = (N + 127) / 128;
  for (int l = 0; l < LL; l++) {
    const float* Wk_l = pWk + (size_t)l * CD * CD;
    const float* bk_l = pbk + (size_t)l * CD;
    const float* Wq_l = pWq + (size_t)l * CD * CD;
    const float* bq_l = pbq + (size_t)l * CD;
    const float* Wv_l = pWv + (size_t)l * CD * CD;
    const float* bv_l = pbv + (size_t)l * CD;
    const float* ar_l = par + (size_t)l * HH * DH * DH;
    const float* mr_l = pmr + (size_t)l * HH * DH * DH;
    const float* pr_l = ppr + (size_t)l * HH;
    const float* Wa_l = pWa + (size_t)l * CD * CD;
    const float* ba_l = pba + (size_t)l * CD;

    // fold relation transforms into K/V weights
    k_eff_w<<<dim3(CD, HH), DH, 0, stream>>>(Wk_l, ar_l, wkeff);
    k_eff_w<<<dim3(CD, HH), DH, 0, stream>>>(Wv_l, mr_l, wveff);
    k_eff_b<<<HH, DH, 0, stream>>>(bk_l, ar_l, bkeff);
    k_eff_b<<<HH, DH, 0, stream>>>(bv_l, mr_l, bveff);

    // q/k/v projections
    k_gemm<false><<<gemmBlocks, 256, 0, stream>>>(hbuf, Wq_l, bq_l, qbuf, N);
    k_gemm<false><<<gemmBlocks, 256, 0, stream>>>(hbuf, wkeff, bkeff, kbuf, N);
    k_gemm<false><<<gemmBlocks, 256, 0, stream>>>(hbuf, wveff, bveff, vbuf, N);

    // fused edge phase -> agg (overwrites qbuf)
    float* agg = qbuf;
    k_edge<<<(N + 3) / 4, 256, 0, stream>>>(qbuf, kbuf, vbuf, rowptr, deg,
                                            csr_src, pr_l, agg, N);

    // out = gelu(agg) @ Wa + ba -> kbuf; then gated residual into hbuf
    k_gemm<true><<<gemmBlocks, 256, 0, stream>>>(agg, Wa_l, ba_l, kbuf, N);
    k_gate<<<((int)(NC / 4) + 255) / 256, 256, 0, stream>>>(hbuf, kbuf, pskip + l, (int)(NC / 4));
  }
  k_final<<<(N + 7) / 8, 256, 0, stream>>>(hbuf, pWfc, pbfc, d_out, flags, N);
}